// Round 1
// baseline (1408.204 us; speedup 1.0000x reference)
//
#include <hip/hip_runtime.h>

#define N_NODES 100000
#define N_EDGES 1600000
#define D 128

#define SCAN_CHUNK 1024
#define SCAN_BLOCKS ((N_NODES + SCAN_CHUNK - 1) / SCAN_CHUNK)  // 98

typedef unsigned long long u64;

// ---------------------------------------------------------------------------
// GEMM: h[n][c] = sum_k x[n][k] * W[k][c]   (unchanged from verified version)
// ---------------------------------------------------------------------------
__global__ __launch_bounds__(256) void gemm_kernel(const float* __restrict__ x,
                                                   const float* __restrict__ W,
                                                   float* __restrict__ h) {
    __shared__ float xs[64][132];
    __shared__ float Wt[128][64];

    const int tid = threadIdx.x;
    const int nodeBase = blockIdx.y * 64;
    const int colBase  = blockIdx.x * 64;

    #pragma unroll
    for (int rep = 0; rep < 8; ++rep) {
        int idx  = tid + rep * 256;
        int node = idx >> 5;
        int kk   = idx & 31;
        int gn   = nodeBase + node;
        float4 v = make_float4(0.f, 0.f, 0.f, 0.f);
        if (gn < N_NODES) v = *(const float4*)(x + (size_t)gn * D + kk * 4);
        *(float4*)(&xs[node][kk * 4]) = v;
    }
    #pragma unroll
    for (int rep = 0; rep < 8; ++rep) {
        int idx = tid + rep * 256;
        int k   = idx >> 4;
        int cc  = idx & 15;
        float4 v = *(const float4*)(W + (size_t)k * D + colBase + cc * 4);
        *(float4*)(&Wt[k][cc * 4]) = v;
    }
    __syncthreads();

    const int ty = tid >> 4;
    const int tx = tid & 15;
    const int n0 = ty * 4;
    const int c0 = tx * 4;

    float acc[4][4];
    #pragma unroll
    for (int i = 0; i < 4; ++i)
        #pragma unroll
        for (int j = 0; j < 4; ++j) acc[i][j] = 0.f;

    #pragma unroll 4
    for (int k = 0; k < D; ++k) {
        float a0 = xs[n0 + 0][k];
        float a1 = xs[n0 + 1][k];
        float a2 = xs[n0 + 2][k];
        float a3 = xs[n0 + 3][k];
        float4 b = *(const float4*)(&Wt[k][c0]);
        acc[0][0] += a0 * b.x; acc[0][1] += a0 * b.y; acc[0][2] += a0 * b.z; acc[0][3] += a0 * b.w;
        acc[1][0] += a1 * b.x; acc[1][1] += a1 * b.y; acc[1][2] += a1 * b.z; acc[1][3] += a1 * b.w;
        acc[2][0] += a2 * b.x; acc[2][1] += a2 * b.y; acc[2][2] += a2 * b.z; acc[2][3] += a2 * b.w;
        acc[3][0] += a3 * b.x; acc[3][1] += a3 * b.y; acc[3][2] += a3 * b.z; acc[3][3] += a3 * b.w;
    }

    #pragma unroll
    for (int i = 0; i < 4; ++i) {
        int gn = nodeBase + n0 + i;
        if (gn < N_NODES) {
            float4 v = make_float4(acc[i][0], acc[i][1], acc[i][2], acc[i][3]);
            *(float4*)(h + (size_t)gn * D + colBase + c0) = v;
        }
    }
}

// ---------------------------------------------------------------------------
// Counting-sort pipeline: histogram -> exclusive scan -> reorder
// ---------------------------------------------------------------------------
__global__ __launch_bounds__(256) void zero_cnt_kernel(int* __restrict__ cnt) {
    int i = blockIdx.x * 256 + threadIdx.x;
    if (i < N_NODES) cnt[i] = 0;
}

__global__ __launch_bounds__(256) void hist_kernel(const int* __restrict__ ei,
                                                   int* __restrict__ cnt) {
    int e = blockIdx.x * 256 + threadIdx.x;
    if (e >= N_EDGES) return;
    atomicAdd(&cnt[ei[N_EDGES + e]], 1);
}

// per-1024-chunk exclusive scan; chunk totals -> bsum
__global__ __launch_bounds__(256) void scan1_kernel(const int* __restrict__ cnt,
                                                    int* __restrict__ off,
                                                    int* __restrict__ bsum) {
    __shared__ int s[256];
    int b = blockIdx.x, t = threadIdx.x;
    int base = b * SCAN_CHUNK + t * 4;
    int c0 = 0, c1 = 0, c2 = 0, c3 = 0;
    if (base + 0 < N_NODES) c0 = cnt[base + 0];
    if (base + 1 < N_NODES) c1 = cnt[base + 1];
    if (base + 2 < N_NODES) c2 = cnt[base + 2];
    if (base + 3 < N_NODES) c3 = cnt[base + 3];
    int tsum = c0 + c1 + c2 + c3;
    s[t] = tsum;
    __syncthreads();
    for (int d = 1; d < 256; d <<= 1) {
        int v = (t >= d) ? s[t - d] : 0;
        __syncthreads();
        s[t] += v;
        __syncthreads();
    }
    int excl = s[t] - tsum;
    if (t == 255) bsum[b] = s[255];
    int e0 = excl, e1 = e0 + c0, e2 = e1 + c1, e3 = e2 + c2;
    if (base + 0 < N_NODES) off[base + 0] = e0;
    if (base + 1 < N_NODES) off[base + 1] = e1;
    if (base + 2 < N_NODES) off[base + 2] = e2;
    if (base + 3 < N_NODES) off[base + 3] = e3;
}

// single-block exclusive scan of the 98 chunk totals (in place)
__global__ __launch_bounds__(128) void scan2_kernel(int* __restrict__ bsum) {
    __shared__ int s[128];
    int t = threadIdx.x;
    int v = (t < SCAN_BLOCKS) ? bsum[t] : 0;
    s[t] = v;
    __syncthreads();
    for (int d = 1; d < 128; d <<= 1) {
        int u = (t >= d) ? s[t - d] : 0;
        __syncthreads();
        s[t] += u;
        __syncthreads();
    }
    if (t < SCAN_BLOCKS) bsum[t] = s[t] - v;  // exclusive
}

// add chunk offsets; init cursor (reusing cnt buffer); write off[N_NODES]
__global__ __launch_bounds__(256) void scan3_kernel(int* __restrict__ off,
                                                    int* __restrict__ cnt,  // becomes cursor
                                                    const int* __restrict__ bsum) {
    int b = blockIdx.x, t = threadIdx.x;
    int boff = bsum[b];
    int base = b * SCAN_CHUNK + t * 4;
    #pragma unroll
    for (int k = 0; k < 4; ++k) {
        int i = base + k;
        if (i < N_NODES) {
            int v = off[i] + boff;
            off[i] = v;
            if (i == N_NODES - 1) off[N_NODES] = v + cnt[i];  // read count BEFORE cursor overwrite
            cnt[i] = v;                                        // cursor = start offset
        }
    }
}

__global__ __launch_bounds__(256) void reorder_kernel(const int* __restrict__ ei,
                                                      int* __restrict__ cur,
                                                      int* __restrict__ perm) {
    int e = blockIdx.x * 256 + threadIdx.x;
    if (e >= N_EDGES) return;
    int d = ei[N_EDGES + e];
    int p = atomicAdd(&cur[d], 1);
    perm[p] = e;
}

// ---------------------------------------------------------------------------
// aggregate: one 64-lane wave per destination node, float2 per lane (128 cols).
// Lanes cooperatively preload up to 64 (perm, src) pairs, then broadcast via
// shfl -> the per-edge load chain is 1 level deep. acc starts at bias; single
// non-atomic row store (subsumes init_out). ea is read-once -> nontemporal.
// ---------------------------------------------------------------------------
__global__ __launch_bounds__(256) void aggregate_kernel(const float* __restrict__ h,
                                                        const int* __restrict__ ei,
                                                        const float* __restrict__ ea,
                                                        const int* __restrict__ off,
                                                        const int* __restrict__ perm,
                                                        const float* __restrict__ bias,
                                                        float* __restrict__ out) {
    int wid  = (blockIdx.x * 256 + threadIdx.x) >> 6;
    int lane = threadIdx.x & 63;
    if (wid >= N_NODES) return;

    int beg = off[wid];
    int end = off[wid + 1];

    float2 acc = *(const float2*)(bias + lane * 2);

    for (int base = beg; base < end; base += 64) {
        int cnt = end - base;
        if (cnt > 64) cnt = 64;
        int myE = 0, mySrc = 0;
        if (lane < cnt) {
            myE   = perm[base + lane];
            mySrc = ei[myE];
        }
        for (int j = 0; j < cnt; ++j) {
            int e   = __shfl(myE, j);
            int src = __shfl(mySrc, j);
            u64 raw = __builtin_nontemporal_load(
                (const u64*)(ea + (size_t)e * D + lane * 2));
            float2 a;
            __builtin_memcpy(&a, &raw, 8);
            float2 hv = *(const float2*)(h + (size_t)src * D + lane * 2);
            acc.x += fmaxf(a.x + hv.x, 0.f);
            acc.y += fmaxf(a.y + hv.y, 0.f);
        }
    }

    u64 o;
    __builtin_memcpy(&o, &acc, 8);
    __builtin_nontemporal_store(o, (u64*)(out + (size_t)wid * D + lane * 2));
}

// ---------------------------------------------------------------------------
// Fallback path (only used if workspace is too small for the CSR scratch):
// verified atomic-scatter implementation from the previous session.
// ---------------------------------------------------------------------------
__global__ __launch_bounds__(256) void init_out_kernel(const float* __restrict__ bias,
                                                       float* __restrict__ out) {
    int t = blockIdx.x * 256 + threadIdx.x;
    if (t >= N_NODES * D / 4) return;
    int c = (t & 31) * 4;
    float4 b = *(const float4*)(bias + c);
    *(float4*)(out + (size_t)t * 4) = b;
}

__global__ __launch_bounds__(256) void scatter_kernel(const float* __restrict__ h,
                                                      const int* __restrict__ ei,
                                                      const float* __restrict__ ea,
                                                      float* __restrict__ out) {
    int t = blockIdx.x * 256 + threadIdx.x;
    int e = t >> 5;
    int l = t & 31;
    if (e >= N_EDGES) return;

    int src = ei[e];
    int dst = ei[N_EDGES + e];

    float4 m  = *(const float4*)(ea + (size_t)e * D + l * 4);
    float4 hv = *(const float4*)(h + (size_t)src * D + l * 4);

    float v0 = fmaxf(m.x + hv.x, 0.f);
    float v1 = fmaxf(m.y + hv.y, 0.f);
    float v2 = fmaxf(m.z + hv.z, 0.f);
    float v3 = fmaxf(m.w + hv.w, 0.f);

    float* op = out + (size_t)dst * D + l * 4;
    unsafeAtomicAdd(op + 0, v0);
    unsafeAtomicAdd(op + 1, v1);
    unsafeAtomicAdd(op + 2, v2);
    unsafeAtomicAdd(op + 3, v3);
}

extern "C" void kernel_launch(void* const* d_in, const int* in_sizes, int n_in,
                              void* d_out, int out_size, void* d_ws, size_t ws_size,
                              hipStream_t stream) {
    const float* x    = (const float*)d_in[0];
    const int*   ei   = (const int*)d_in[1];
    const float* ea   = (const float*)d_in[2];
    const float* W    = (const float*)d_in[3];
    const float* bias = (const float*)d_in[4];
    float* out = (float*)d_out;

    // workspace layout
    const size_t H_BYTES    = (size_t)N_NODES * D * 4;   // 51,200,000
    const size_t CNT_OFF    = H_BYTES;
    const size_t CNT_BYTES  = 400128;                    // N_NODES ints, rounded
    const size_t OFF_OFF    = CNT_OFF + CNT_BYTES;
    const size_t OFF_BYTES  = 400384;                    // N_NODES+1 ints, rounded
    const size_t BSUM_OFF   = OFF_OFF + OFF_BYTES;
    const size_t BSUM_BYTES = 512;                       // 98 ints, rounded
    const size_t PERM_OFF   = BSUM_OFF + BSUM_BYTES;
    const size_t PERM_BYTES = (size_t)N_EDGES * 4;       // 6,400,000
    const size_t NEED       = PERM_OFF + PERM_BYTES;     // ~58.4 MB

    float* h = (float*)d_ws;

    dim3 gGemm(2, (N_NODES + 63) / 64);
    gemm_kernel<<<gGemm, 256, 0, stream>>>(x, W, h);

    if (ws_size >= NEED) {
        int* cnt  = (int*)((char*)d_ws + CNT_OFF);   // counts, then cursor
        int* off  = (int*)((char*)d_ws + OFF_OFF);
        int* bsum = (int*)((char*)d_ws + BSUM_OFF);
        int* perm = (int*)((char*)d_ws + PERM_OFF);

        zero_cnt_kernel<<<(N_NODES + 255) / 256, 256, 0, stream>>>(cnt);
        hist_kernel<<<N_EDGES / 256, 256, 0, stream>>>(ei, cnt);
        scan1_kernel<<<SCAN_BLOCKS, 256, 0, stream>>>(cnt, off, bsum);
        scan2_kernel<<<1, 128, 0, stream>>>(bsum);
        scan3_kernel<<<SCAN_BLOCKS, 256, 0, stream>>>(off, cnt, bsum);
        reorder_kernel<<<N_EDGES / 256, 256, 0, stream>>>(ei, cnt, perm);

        int aggBlocks = (N_NODES * 64 + 255) / 256;  // 25000
        aggregate_kernel<<<aggBlocks, 256, 0, stream>>>(h, ei, ea, off, perm, bias, out);
    } else {
        // fallback: previous verified atomic path
        init_out_kernel<<<(N_NODES * D / 4 + 255) / 256, 256, 0, stream>>>(bias, out);
        int scatterBlocks = (N_EDGES * 32 + 255) / 256;
        scatter_kernel<<<scatterBlocks, 256, 0, stream>>>(h, ei, ea, out);
    }
}